// Round 1
// baseline (1637.638 us; speedup 1.0000x reference)
//
#include <hip/hip_runtime.h>

#define N_NODES 100000
#define N_EDGES 600000
#define NODE_DIM 64
#define EDGE_DIM 32
#define HID 128
#define OUT_DIM 24

typedef short short8 __attribute__((ext_vector_type(8)));
typedef short short4v __attribute__((ext_vector_type(4)));
typedef float f32x4 __attribute__((ext_vector_type(4)));

#define MFMA16(a, b, c) __builtin_amdgcn_mfma_f32_16x16x32_bf16(a, b, c, 0, 0, 0)

__device__ inline unsigned short f2bf(float f) {
  unsigned u = __float_as_uint(f);
  u += 0x7FFFu + ((u >> 16) & 1u);
  return (unsigned short)(u >> 16);
}
__device__ inline float bf2f(unsigned short b) {
  return __uint_as_float(((unsigned)b) << 16);
}

// ---- prepped weight region layout (ushort units) ----
#define OFF_CW1T 0                       // cls w1^T bf16 [128][288]
#define OFF_CW2T 36864                   // cls w2^T bf16 [32 pad][128]
#define OFF_LAYER(c) (40960 + (c)*65536) // per conv: w1t_hi,w1t_lo,w2t_hi,w2t_lo each [128][128]
#define W_TOTAL 237568

__global__ __launch_bounds__(256) void prep_weights(
    const float* __restrict__ cw1, const float* __restrict__ cw2,
    const float* __restrict__ l0w1, const float* __restrict__ l0w2,
    const float* __restrict__ l1w1, const float* __restrict__ l1w2,
    const float* __restrict__ l2w1, const float* __restrict__ l2w2,
    unsigned short* __restrict__ wb) {
  int i = blockIdx.x * 256 + threadIdx.x;
  if (i < 36864) {                       // cls w1t[n][k] = cw1[k][n]
    int n = i / 288, k = i % 288;
    wb[OFF_CW1T + i] = f2bf(cw1[k * 128 + n]);
  }
  int j = i - 36864;
  if (j >= 0 && j < 4096) {              // cls w2t[n][k], n padded to 32
    int n = j / 128, k = j % 128;
    wb[OFF_CW2T + j] = f2bf(n < 24 ? cw2[k * 24 + n] : 0.f);
  }
  int t = i - 40960;
  if (t >= 0 && t < 3 * 32768) {         // conv layers, split hi/lo
    int c = t / 32768, u = t % 32768;
    const float* w = (u < 16384) ? (c == 0 ? l0w1 : c == 1 ? l1w1 : l2w1)
                                 : (c == 0 ? l0w2 : c == 1 ? l1w2 : l2w2);
    int v = u & 16383;
    int n = v >> 7, k = v & 127;
    float val = w[k * 128 + n];
    unsigned short hi = f2bf(val);
    unsigned short lo = f2bf(val - bf2f(hi));
    int base = OFF_LAYER(c) + (u < 16384 ? 0 : 32768);
    wb[base + v] = hi;
    wb[base + 16384 + v] = lo;
  }
}

// ================= lin1: h = x @ w + b  (K=64, fp32) =================
__global__ __launch_bounds__(256) void lin1_kernel(
    const float* __restrict__ x, const float* __restrict__ w,
    const float* __restrict__ b, float* __restrict__ h) {
  __shared__ float4 smem4[3072];
  float* sA = (float*)smem4;
  float* sB = (float*)smem4 + 4096;
  int tid = threadIdx.x;
  int tn = tid & 31, tm = tid >> 5;
  int mbase = blockIdx.x * 64;

  for (int i = tid; i < 1024; i += 256) {
    int m = i & 63, k4 = (i >> 6) << 2;
    int row = mbase + m; if (row >= N_NODES) row = N_NODES - 1;
    float4 v = *(const float4*)(x + (size_t)row * NODE_DIM + k4);
    sA[(k4 + 0) * 64 + m] = v.x; sA[(k4 + 1) * 64 + m] = v.y;
    sA[(k4 + 2) * 64 + m] = v.z; sA[(k4 + 3) * 64 + m] = v.w;
  }
  for (int i = tid; i < 2048; i += 256)
    *(float4*)&sB[i * 4] = ((const float4*)w)[i];
  __syncthreads();

  float acc[8][4] = {};
#pragma unroll 8
  for (int k = 0; k < 64; ++k) {
    float4 a0 = *(float4*)&sA[k * 64 + tm * 8];
    float4 a1 = *(float4*)&sA[k * 64 + tm * 8 + 4];
    float4 bv = *(float4*)&sB[k * 128 + tn * 4];
    float av[8] = {a0.x, a0.y, a0.z, a0.w, a1.x, a1.y, a1.z, a1.w};
    float bb[4] = {bv.x, bv.y, bv.z, bv.w};
#pragma unroll
    for (int i = 0; i < 8; ++i)
#pragma unroll
      for (int jj = 0; jj < 4; ++jj) acc[i][jj] = fmaf(av[i], bb[jj], acc[i][jj]);
  }
  float4 bv = *(const float4*)(b + tn * 4);
#pragma unroll
  for (int i = 0; i < 8; ++i) {
    int row = mbase + tm * 8 + i;
    if (row < N_NODES) {
      float4 o = {acc[i][0] + bv.x, acc[i][1] + bv.y, acc[i][2] + bv.z, acc[i][3] + bv.w};
      *(float4*)(h + (size_t)row * HID + tn * 4) = o;
    }
  }
}

// ======================= CSR build =======================
__global__ __launch_bounds__(256) void hist_kernel(
    const int* __restrict__ dst, int* __restrict__ counts) {
  int e = blockIdx.x * 256 + threadIdx.x;
  if (e < N_EDGES) atomicAdd(&counts[dst[e]], 1);
}

#define SCAN_BLK 98  // ceil(100000/1024)
__global__ __launch_bounds__(256) void scan_partial(
    const int* __restrict__ cnt, int* __restrict__ partial) {
  __shared__ int sdata[256];
  int b = blockIdx.x, t = threadIdx.x;
  int sum = 0;
  for (int i = t; i < 1024; i += 256) {
    int idx = b * 1024 + i;
    sum += (idx < N_NODES) ? cnt[idx] : 0;
  }
  sdata[t] = sum; __syncthreads();
  for (int s = 128; s > 0; s >>= 1) {
    if (t < s) sdata[t] += sdata[t + s];
    __syncthreads();
  }
  if (t == 0) partial[b] = sdata[0];
}

__global__ void scan_sums(const int* __restrict__ partial,
                          int* __restrict__ partialScan, int* __restrict__ rowptr) {
  if (threadIdx.x == 0) {
    int acc = 0;
    for (int i = 0; i < SCAN_BLK; ++i) { partialScan[i] = acc; acc += partial[i]; }
    rowptr[N_NODES] = acc;
  }
}

__global__ __launch_bounds__(256) void scan_final(
    const int* __restrict__ cnt, const int* __restrict__ partialScan,
    int* __restrict__ rowptr, int* __restrict__ cur) {
  __shared__ int sdata[256];
  int b = blockIdx.x, t = threadIdx.x;
  int i0 = b * 1024 + t * 4;
  int c[4]; int s = 0;
#pragma unroll
  for (int j = 0; j < 4; ++j) {
    c[j] = (i0 + j < N_NODES) ? cnt[i0 + j] : 0;
    s += c[j];
  }
  sdata[t] = s; __syncthreads();
  for (int d = 1; d < 256; d <<= 1) {
    int u = (t >= d) ? sdata[t - d] : 0;
    __syncthreads();
    sdata[t] += u;
    __syncthreads();
  }
  int off = sdata[t] - s + partialScan[b];
#pragma unroll
  for (int j = 0; j < 4; ++j) {
    int idx = i0 + j;
    if (idx < N_NODES) { rowptr[idx] = off; cur[idx] = off; off += c[j]; }
  }
}

// scatter also materializes src_perm[slot] = src[e] so the agg loop has
// one fewer dependent load (perm[i] -> src[e] hop removed).
__global__ __launch_bounds__(256) void scatter_kernel(
    const int* __restrict__ dst, const int* __restrict__ src,
    int* __restrict__ cur, int* __restrict__ perm, int* __restrict__ srcp) {
  int e = blockIdx.x * 256 + threadIdx.x;
  if (e < N_EDGES) {
    int slot = atomicAdd(&cur[dst[e]], 1);
    perm[slot] = e;
    srcp[slot] = src[e];
  }
}

// ======== aggregation: one wave per dst node, no atomics ========
// Latency-bound fix: src_perm removes one dependent load; 2-edge unroll puts
// two h-gathers + two ea rows in flight and amortizes the ew broadcast loads;
// grid 2048 blocks -> full 8192-wave residency.
__global__ __launch_bounds__(256) void agg_gather_kernel(
    const float* __restrict__ h, const float* __restrict__ ea,
    const int* __restrict__ srcp, const int* __restrict__ perm,
    const int* __restrict__ rowptr,
    const float* __restrict__ ew, const float* __restrict__ eb,
    float* __restrict__ agg) {
  int tid = threadIdx.x, lane = tid & 63;
  int wid = blockIdx.x * 4 + (tid >> 6);
  int nwaves = gridDim.x * 4;
  const float2* ew2 = (const float2*)ew;  // ew2[k*64 + lane] = ew[k][2l..2l+1]
  float2 ebv = *(const float2*)(eb + lane * 2);

  for (int node = wid; node < N_NODES; node += nwaves) {
    int beg = rowptr[node], end = rowptr[node + 1];
    float2 acc = {0.f, 0.f};
    int i = beg;
    for (; i + 1 < end; i += 2) {
      int s0 = srcp[i], s1 = srcp[i + 1];
      int e0 = perm[i], e1 = perm[i + 1];
      float2 h0 = *(const float2*)(h + (size_t)s0 * HID + lane * 2);
      float2 h1 = *(const float2*)(h + (size_t)s1 * HID + lane * 2);
      const float4* ea0 = (const float4*)(ea + (size_t)e0 * EDGE_DIM);
      const float4* ea1 = (const float4*)(ea + (size_t)e1 * EDGE_DIM);
      float2 m0 = ebv, m1 = ebv;
#pragma unroll
      for (int k4 = 0; k4 < 8; ++k4) {
        float4 a0 = ea0[k4], a1 = ea1[k4];
        float a0v[4] = {a0.x, a0.y, a0.z, a0.w};
        float a1v[4] = {a1.x, a1.y, a1.z, a1.w};
#pragma unroll
        for (int j = 0; j < 4; ++j) {
          float2 w = ew2[(k4 * 4 + j) * 64 + lane];
          m0.x = fmaf(a0v[j], w.x, m0.x);
          m0.y = fmaf(a0v[j], w.y, m0.y);
          m1.x = fmaf(a1v[j], w.x, m1.x);
          m1.y = fmaf(a1v[j], w.y, m1.y);
        }
      }
      acc.x += fmaxf(m0.x + h0.x, 0.f) + fmaxf(m1.x + h1.x, 0.f);
      acc.y += fmaxf(m0.y + h0.y, 0.f) + fmaxf(m1.y + h1.y, 0.f);
    }
    if (i < end) {
      int s0 = srcp[i];
      int e0 = perm[i];
      float2 h0 = *(const float2*)(h + (size_t)s0 * HID + lane * 2);
      const float4* ea0 = (const float4*)(ea + (size_t)e0 * EDGE_DIM);
      float2 m0 = ebv;
#pragma unroll
      for (int k4 = 0; k4 < 8; ++k4) {
        float4 a0 = ea0[k4];
        float a0v[4] = {a0.x, a0.y, a0.z, a0.w};
#pragma unroll
        for (int j = 0; j < 4; ++j) {
          float2 w = ew2[(k4 * 4 + j) * 64 + lane];
          m0.x = fmaf(a0v[j], w.x, m0.x);
          m0.y = fmaf(a0v[j], w.y, m0.y);
        }
      }
      acc.x += fmaxf(m0.x + h0.x, 0.f);
      acc.y += fmaxf(m0.y + h0.y, 0.f);
    }
    *(float2*)(agg + (size_t)node * HID + lane * 2) = acc;
  }
}

// ======== node MLP via split-bf16 MFMA ========
__global__ __launch_bounds__(256) void mlp_mfma(
    const float* __restrict__ h, const float* __restrict__ agg,
    const unsigned short* __restrict__ wl,
    const float* __restrict__ b1, const float* __restrict__ b2,
    float* __restrict__ hout) {
  __shared__ unsigned short lds[40960];  // 80 KB
  unsigned short* sAh = lds;
  unsigned short* sAl = lds + 4096;
  unsigned short* sBh = lds + 8192;
  unsigned short* sBl = lds + 12288;
  unsigned short* t1h = lds;
  unsigned short* t1l = lds + 16384;
  unsigned short* sB2h = lds + 32768;
  unsigned short* sB2l = lds + 36864;
  const unsigned short* w1h = wl;
  const unsigned short* w1l = wl + 16384;
  const unsigned short* w2h = wl + 32768;
  const unsigned short* w2l = wl + 49152;
  int tid = threadIdx.x, lane = tid & 63, wave = tid >> 6;
  int wm = wave & 1, wn = wave >> 1;
  int mbase = blockIdx.x * 128;
  const f32x4 zf = {0.f, 0.f, 0.f, 0.f};

  f32x4 acc[4][4];
#pragma unroll
  for (int a = 0; a < 4; ++a)
#pragma unroll
    for (int bq = 0; bq < 4; ++bq) acc[a][bq] = zf;

  for (int c = 0; c < 4; ++c) {
    __syncthreads();
#pragma unroll
    for (int it = 0; it < 4; ++it) {
      int idx = it * 256 + tid;
      int m = idx >> 3, k4 = (idx & 7) * 4;
      int row = mbase + m; if (row >= N_NODES) row = N_NODES - 1;
      size_t g = (size_t)row * HID + c * 32 + k4;
      float4 hv = *(const float4*)(h + g);
      float4 av = *(const float4*)(agg + g);
      float z0 = hv.x + av.x, z1 = hv.y + av.y, z2 = hv.z + av.z, z3 = hv.w + av.w;
      unsigned short h0 = f2bf(z0), h1 = f2bf(z1), h2 = f2bf(z2), h3 = f2bf(z3);
      int slot = ((m >> 4) * 4 + (k4 >> 3)) * 16 + (m & 15);
      int off = slot * 8 + (k4 & 7);
      short4v ph = {(short)h0, (short)h1, (short)h2, (short)h3};
      short4v pl = {(short)f2bf(z0 - bf2f(h0)), (short)f2bf(z1 - bf2f(h1)),
                    (short)f2bf(z2 - bf2f(h2)), (short)f2bf(z3 - bf2f(h3))};
      *(short4v*)(sAh + off) = ph;
      *(short4v*)(sAl + off) = pl;
    }
#pragma unroll
    for (int it = 0; it < 2; ++it) {
      int s = it * 256 + tid;
      int ntile = s >> 6, kgrp = (s >> 4) & 3, nrow = s & 15;
      int goff = (ntile * 16 + nrow) * 128 + c * 32 + kgrp * 8;
      *(short8*)(sBh + s * 8) = *(const short8*)(w1h + goff);
      *(short8*)(sBl + s * 8) = *(const short8*)(w1l + goff);
    }
    __syncthreads();
    short8 ah[4], al[4], bh[4], bl[4];
#pragma unroll
    for (int mt = 0; mt < 4; ++mt) {
      ah[mt] = *(short8*)(sAh + ((wm * 4 + mt) * 64 + lane) * 8);
      al[mt] = *(short8*)(sAl + ((wm * 4 + mt) * 64 + lane) * 8);
    }
#pragma unroll
    for (int nt = 0; nt < 4; ++nt) {
      bh[nt] = *(short8*)(sBh + ((wn * 4 + nt) * 64 + lane) * 8);
      bl[nt] = *(short8*)(sBl + ((wn * 4 + nt) * 64 + lane) * 8);
    }
#pragma unroll
    for (int mt = 0; mt < 4; ++mt)
#pragma unroll
      for (int nt = 0; nt < 4; ++nt) {
        acc[mt][nt] = MFMA16(ah[mt], bh[nt], acc[mt][nt]);
        acc[mt][nt] = MFMA16(ah[mt], bl[nt], acc[mt][nt]);
        acc[mt][nt] = MFMA16(al[mt], bh[nt], acc[mt][nt]);
      }
  }
  __syncthreads();
  int q = lane >> 4, r = lane & 15;
#pragma unroll
  for (int nt = 0; nt < 4; ++nt) {
    int n = wn * 64 + nt * 16 + r;
    float b1v = b1[n];
    int kgrp = n >> 3, jj = n & 7;
#pragma unroll
    for (int mt = 0; mt < 4; ++mt) {
      int mtg = wm * 4 + mt;
#pragma unroll
      for (int i2 = 0; i2 < 4; ++i2) {
        int mrow = q * 4 + i2;
        float val = fmaxf(acc[mt][nt][i2] + b1v, 0.f);
        unsigned short hi = f2bf(val);
        int idx = ((mtg * 16 + kgrp) * 16 + mrow) * 8 + jj;
        t1h[idx] = hi;
        t1l[idx] = f2bf(val - bf2f(hi));
      }
    }
  }

  f32x4 acc2[4][4];
#pragma unroll
  for (int a = 0; a < 4; ++a)
#pragma unroll
    for (int bq = 0; bq < 4; ++bq) acc2[a][bq] = zf;

  for (int kc = 0; kc < 4; ++kc) {
    __syncthreads();
#pragma unroll
    for (int it = 0; it < 2; ++it) {
      int s = it * 256 + tid;
      int ntile = s >> 6, kgrp = (s >> 4) & 3, nrow = s & 15;
      int goff = (ntile * 16 + nrow) * 128 + kc * 32 + kgrp * 8;
      *(short8*)(sB2h + s * 8) = *(const short8*)(w2h + goff);
      *(short8*)(sB2l + s * 8) = *(const short8*)(w2l + goff);
    }
    __syncthreads();
    short8 ah[4], al[4], bh[4], bl[4];
#pragma unroll
    for (int mt = 0; mt < 4; ++mt) {
      int mtg = wm * 4 + mt;
      int idx = ((mtg * 16 + kc * 4 + q) * 16 + r) * 8;
      ah[mt] = *(short8*)(t1h + idx);
      al[mt] = *(short8*)(t1l + idx);
    }
#pragma unroll
    for (int nt = 0; nt < 4; ++nt) {
      bh[nt] = *(short8*)(sB2h + ((wn * 4 + nt) * 64 + lane) * 8);
      bl[nt] = *(short8*)(sB2l + ((wn * 4 + nt) * 64 + lane) * 8);
    }
#pragma unroll
    for (int mt = 0; mt < 4; ++mt)
#pragma unroll
      for (int nt = 0; nt < 4; ++nt) {
        acc2[mt][nt] = MFMA16(ah[mt], bh[nt], acc2[mt][nt]);
        acc2[mt][nt] = MFMA16(ah[mt], bl[nt], acc2[mt][nt]);
        acc2[mt][nt] = MFMA16(al[mt], bh[nt], acc2[mt][nt]);
      }
  }
#pragma unroll
  for (int nt = 0; nt < 4; ++nt) {
    int n = wn * 64 + nt * 16 + r;
    float b2v = b2[n];
#pragma unroll
    for (int mt = 0; mt < 4; ++mt) {
      int mtg = wm * 4 + mt;
#pragma unroll
      for (int i2 = 0; i2 < 4; ++i2) {
        int row = mbase + mtg * 16 + q * 4 + i2;
        if (row < N_NODES)
          hout[(size_t)row * HID + n] = fmaxf(acc2[mt][nt][i2] + b2v, 0.f);
      }
    }
  }
}

// ======== classifier via bf16 MFMA ========
__global__ __launch_bounds__(256) void cls_mfma(
    const float* __restrict__ h, const float* __restrict__ ea,
    const int* __restrict__ src, const int* __restrict__ dst,
    const unsigned short* __restrict__ w1t, const unsigned short* __restrict__ w2t,
    const float* __restrict__ b1, const float* __restrict__ b2,
    float* __restrict__ out) {
  __shared__ unsigned short lds[20480];  // 40 KB
  unsigned short* sA = lds;
  unsigned short* sB = lds + 4096;
  unsigned short* t1 = lds;
  unsigned short* sB2 = lds + 16384;
  __shared__ int sidx[256];
  int tid = threadIdx.x, lane = tid & 63, wave = tid >> 6;
  int wm = wave & 1, wn = wave >> 1;
  int ebase = blockIdx.x * 128;
  const f32x4 zf = {0.f, 0.f, 0.f, 0.f};

  {
    int e0 = ebase + (tid & 127);
    if (e0 >= N_EDGES) e0 = N_EDGES - 1;
    sidx[tid] = (tid < 128 ? src : dst)[e0];
  }

  f32x4 acc[4][4];
#pragma unroll
  for (int a = 0; a < 4; ++a)
#pragma unroll
    for (int bq = 0; bq < 4; ++bq) acc[a][bq] = zf;

  for (int c = 0; c < 9; ++c) {
    __syncthreads();
#pragma unroll
    for (int it = 0; it < 4; ++it) {
      int idx = it * 256 + tid;
      int m = idx >> 3, k4 = (idx & 7) * 4;
      const float* rp;
      if (c < 4)      rp = h + (size_t)sidx[m] * HID + c * 32 + k4;
      else if (c < 8) rp = h + (size_t)sidx[128 + m] * HID + (c - 4) * 32 + k4;
      else {
        int e8 = ebase + m; if (e8 >= N_EDGES) e8 = N_EDGES - 1;
        rp = ea + (size_t)e8 * EDGE_DIM + k4;
      }
      float4 v = *(const float4*)rp;
      int slot = ((m >> 4) * 4 + (k4 >> 3)) * 16 + (m & 15);
      short4v pk = {(short)f2bf(v.x), (short)f2bf(v.y), (short)f2bf(v.z), (short)f2bf(v.w)};
      *(short4v*)(sA + slot * 8 + (k4 & 7)) = pk;
    }
#pragma unroll
    for (int it = 0; it < 2; ++it) {
      int s = it * 256 + tid;
      int ntile = s >> 6, kgrp = (s >> 4) & 3, nrow = s & 15;
      *(short8*)(sB + s * 8) = *(const short8*)(w1t + (ntile * 16 + nrow) * 288 + c * 32 + kgrp * 8);
    }
    __syncthreads();
    short8 af[4], bfv[4];
#pragma unroll
    for (int mt = 0; mt < 4; ++mt)
      af[mt] = *(short8*)(sA + ((wm * 4 + mt) * 64 + lane) * 8);
#pragma unroll
    for (int nt = 0; nt < 4; ++nt)
      bfv[nt] = *(short8*)(sB + ((wn * 4 + nt) * 64 + lane) * 8);
#pragma unroll
    for (int mt = 0; mt < 4; ++mt)
#pragma unroll
      for (int nt = 0; nt < 4; ++nt)
        acc[mt][nt] = MFMA16(af[mt], bfv[nt], acc[mt][nt]);
  }
  __syncthreads();
  int q = lane >> 4, r = lane & 15;
#pragma unroll
  for (int nt = 0; nt < 4; ++nt) {
    int n = wn * 64 + nt * 16 + r;
    float b1v = b1[n];
    int kgrp = n >> 3, jj = n & 7;
#pragma unroll
    for (int mt = 0; mt < 4; ++mt) {
      int mtg = wm * 4 + mt;
#pragma unroll
      for (int i2 = 0; i2 < 4; ++i2) {
        int mrow = q * 4 + i2;
        float val = fmaxf(acc[mt][nt][i2] + b1v, 0.f);
        t1[((mtg * 16 + kgrp) * 16 + mrow) * 8 + jj] = f2bf(val);
      }
    }
  }
#pragma unroll
  for (int it = 0; it < 2; ++it) {
    int s = it * 256 + tid;
    int ntile = s >> 8, kgrp = (s >> 4) & 15, nrow = s & 15;
    *(short8*)(sB2 + s * 8) = *(const short8*)(w2t + (ntile * 16 + nrow) * 128 + kgrp * 8);
  }
  __syncthreads();

  f32x4 acc2[2][2];
  acc2[0][0] = zf; acc2[0][1] = zf; acc2[1][0] = zf; acc2[1][1] = zf;
#pragma unroll
  for (int kc = 0; kc < 4; ++kc) {
    short8 a0 = *(short8*)(t1 + (((wave * 2 + 0) * 16 + kc * 4 + q) * 16 + r) * 8);
    short8 a1 = *(short8*)(t1 + (((wave * 2 + 1) * 16 + kc * 4 + q) * 16 + r) * 8);
    short8 b0 = *(short8*)(sB2 + ((0 * 16 + kc * 4 + q) * 16 + r) * 8);
    short8 b1f = *(short8*)(sB2 + ((1 * 16 + kc * 4 + q) * 16 + r) * 8);
    acc2[0][0] = MFMA16(a0, b0, acc2[0][0]);
    acc2[0][1] = MFMA16(a0, b1f, acc2[0][1]);
    acc2[1][0] = MFMA16(a1, b0, acc2[1][0]);
    acc2[1][1] = MFMA16(a1, b1f, acc2[1][1]);
  }
#pragma unroll
  for (int nt2 = 0; nt2 < 2; ++nt2) {
    int n = nt2 * 16 + r;
    float b2v = (n < OUT_DIM) ? b2[n] : 0.f;
#pragma unroll
    for (int mt2 = 0; mt2 < 2; ++mt2) {
      int mtg = wave * 2 + mt2;
#pragma unroll
      for (int i2 = 0; i2 < 4; ++i2) {
        int e = ebase + mtg * 16 + q * 4 + i2;
        if (n < OUT_DIM && e < N_EDGES)
          out[(size_t)e * OUT_DIM + n] = acc2[mt2][nt2][i2] + b2v;
      }
    }
  }
}

extern "C" void kernel_launch(void* const* d_in, const int* in_sizes, int n_in,
                              void* d_out, int out_size, void* d_ws, size_t ws_size,
                              hipStream_t stream) {
  const float* x = (const float*)d_in[0];
  const int* ei = (const int*)d_in[1];
  const float* ea = (const float*)d_in[2];
  const float* lin1_w = (const float*)d_in[3];
  const float* lin1_b = (const float*)d_in[4];
  const int* src = ei;
  const int* dst = ei + N_EDGES;

  const size_t NH = (size_t)N_NODES * HID;
  float* bufA = (float*)d_ws;
  float* bufB = bufA + NH;
  // graph region after bufB (~6 MB)
  int* ibase = (int*)(bufB + NH);
  int* rowptr = ibase;                 // N_NODES+1
  int* cur = ibase + 100004;           // N_NODES
  int* counts = ibase + 200004;        // N_NODES
  int* perm = ibase + 300004;          // N_EDGES
  int* partial = ibase + 900004;       // 128
  int* partialScan = ibase + 900132;   // 128
  int* srcp = ibase + 900260;          // N_EDGES (src of permuted edge)
  // prepped weights at the END of ws
  unsigned short* wbase = (unsigned short*)((((uintptr_t)d_ws + ws_size) - (size_t)W_TOTAL * 2) & ~(uintptr_t)255);

  prep_weights<<<(139264 + 255) / 256, 256, 0, stream>>>(
      (const float*)d_in[23], (const float*)d_in[25],
      (const float*)d_in[7], (const float*)d_in[9],
      (const float*)d_in[13], (const float*)d_in[15],
      (const float*)d_in[19], (const float*)d_in[21], wbase);

  lin1_kernel<<<(N_NODES + 63) / 64, 256, 0, stream>>>(x, lin1_w, lin1_b, bufA);

  // ---- CSR build (once; shared by all 3 layers) ----
  hipMemsetAsync(counts, 0, N_NODES * sizeof(int), stream);
  hist_kernel<<<(N_EDGES + 255) / 256, 256, 0, stream>>>(dst, counts);
  scan_partial<<<SCAN_BLK, 256, 0, stream>>>(counts, partial);
  scan_sums<<<1, 64, 0, stream>>>(partial, partialScan, rowptr);
  scan_final<<<SCAN_BLK, 256, 0, stream>>>(counts, partialScan, rowptr, cur);
  scatter_kernel<<<(N_EDGES + 255) / 256, 256, 0, stream>>>(dst, src, cur, perm, srcp);

  float* hcur = bufA;
  float* aux = bufB;
  for (int c = 0; c < 3; ++c) {
    const float* ew = (const float*)d_in[5 + c * 6 + 0];
    const float* eb = (const float*)d_in[5 + c * 6 + 1];
    const float* b1 = (const float*)d_in[5 + c * 6 + 3];
    const float* b2 = (const float*)d_in[5 + c * 6 + 5];
    agg_gather_kernel<<<2048, 256, 0, stream>>>(
        hcur, ea, srcp, perm, rowptr, ew, eb, aux);
    mlp_mfma<<<(N_NODES + 127) / 128, 256, 0, stream>>>(
        hcur, aux, wbase + OFF_LAYER(c), b1, b2, aux);
    float* tmp = hcur; hcur = aux; aux = tmp;
  }

  const float* cb1 = (const float*)d_in[24];
  const float* cb2 = (const float*)d_in[26];
  cls_mfma<<<(N_EDGES + 127) / 128, 256, 0, stream>>>(
      hcur, ea, src, dst, wbase + OFF_CW1T, wbase + OFF_CW2T, cb1, cb2, (float*)d_out);
}

// Round 2
// 1018.383 us; speedup vs baseline: 1.6081x; 1.6081x over previous
//
#include <hip/hip_runtime.h>

#define N_NODES 100000
#define N_EDGES 600000
#define NODE_DIM 64
#define EDGE_DIM 32
#define HID 128
#define OUT_DIM 24

typedef short short8 __attribute__((ext_vector_type(8)));
typedef short short4v __attribute__((ext_vector_type(4)));
typedef float f32x4 __attribute__((ext_vector_type(4)));

#define MFMA16(a, b, c) __builtin_amdgcn_mfma_f32_16x16x32_bf16(a, b, c, 0, 0, 0)

__device__ inline unsigned short f2bf(float f) {
  unsigned u = __float_as_uint(f);
  u += 0x7FFFu + ((u >> 16) & 1u);
  return (unsigned short)(u >> 16);
}
__device__ inline float bf2f(unsigned short b) {
  return __uint_as_float(((unsigned)b) << 16);
}

// ---- prepped weight region layout (ushort units) ----
#define OFF_CW1T 0                       // cls w1^T bf16 [128][288]
#define OFF_CW2T 36864                   // cls w2^T bf16 [32 pad][128]
#define OFF_LAYER(c) (40960 + (c)*65536) // per conv: w1t_hi,w1t_lo,w2t_hi,w2t_lo each [128][128]
#define OFF_EWT(c) (237568 + (c)*8192)   // per conv: ew^T in MFMA B-frag order, hi[4096]+lo[4096]
#define W_TOTAL 262144

__global__ __launch_bounds__(256) void prep_weights(
    const float* __restrict__ cw1, const float* __restrict__ cw2,
    const float* __restrict__ l0w1, const float* __restrict__ l0w2,
    const float* __restrict__ l1w1, const float* __restrict__ l1w2,
    const float* __restrict__ l2w1, const float* __restrict__ l2w2,
    const float* __restrict__ e0w, const float* __restrict__ e1w,
    const float* __restrict__ e2w,
    unsigned short* __restrict__ wb) {
  int i = blockIdx.x * 256 + threadIdx.x;
  if (i < 36864) {                       // cls w1t[n][k] = cw1[k][n]
    int n = i / 288, k = i % 288;
    wb[OFF_CW1T + i] = f2bf(cw1[k * 128 + n]);
  }
  int j = i - 36864;
  if (j >= 0 && j < 4096) {              // cls w2t[n][k], n padded to 32
    int n = j / 128, k = j % 128;
    wb[OFF_CW2T + j] = f2bf(n < 24 ? cw2[k * 24 + n] : 0.f);
  }
  int t = i - 40960;
  if (t >= 0 && t < 3 * 32768) {         // conv layers, split hi/lo
    int c = t / 32768, u = t % 32768;
    const float* w = (u < 16384) ? (c == 0 ? l0w1 : c == 1 ? l1w1 : l2w1)
                                 : (c == 0 ? l0w2 : c == 1 ? l1w2 : l2w2);
    int v = u & 16383;
    int n = v >> 7, k = v & 127;
    float val = w[k * 128 + n];
    unsigned short hi = f2bf(val);
    unsigned short lo = f2bf(val - bf2f(hi));
    int base = OFF_LAYER(c) + (u < 16384 ? 0 : 32768);
    wb[base + v] = hi;
    wb[base + 16384 + v] = lo;
  }
  int p = i - 139264;
  if (p >= 0 && p < 3 * 8192) {          // ew^T in MFMA B-fragment order, hi/lo
    int c = p / 8192, u = p % 8192;
    int v = u & 4095;
    int s = v >> 3, jj = v & 7;
    int ntile = s >> 6, kgrp = (s >> 4) & 3, nrow = s & 15;
    int n = ntile * 16 + nrow, k = kgrp * 8 + jj;
    const float* ew = (c == 0 ? e0w : c == 1 ? e1w : e2w);
    float val = ew[k * 128 + n];
    unsigned short hi = f2bf(val);
    wb[OFF_EWT(c) + u] = (u < 4096) ? hi : f2bf(val - bf2f(hi));
  }
}

// ================= lin1: h = x @ w + b  (K=64, fp32) =================
__global__ __launch_bounds__(256) void lin1_kernel(
    const float* __restrict__ x, const float* __restrict__ w,
    const float* __restrict__ b, float* __restrict__ h) {
  __shared__ float4 smem4[3072];
  float* sA = (float*)smem4;
  float* sB = (float*)smem4 + 4096;
  int tid = threadIdx.x;
  int tn = tid & 31, tm = tid >> 5;
  int mbase = blockIdx.x * 64;

  for (int i = tid; i < 1024; i += 256) {
    int m = i & 63, k4 = (i >> 6) << 2;
    int row = mbase + m; if (row >= N_NODES) row = N_NODES - 1;
    float4 v = *(const float4*)(x + (size_t)row * NODE_DIM + k4);
    sA[(k4 + 0) * 64 + m] = v.x; sA[(k4 + 1) * 64 + m] = v.y;
    sA[(k4 + 2) * 64 + m] = v.z; sA[(k4 + 3) * 64 + m] = v.w;
  }
  for (int i = tid; i < 2048; i += 256)
    *(float4*)&sB[i * 4] = ((const float4*)w)[i];
  __syncthreads();

  float acc[8][4] = {};
#pragma unroll 8
  for (int k = 0; k < 64; ++k) {
    float4 a0 = *(float4*)&sA[k * 64 + tm * 8];
    float4 a1 = *(float4*)&sA[k * 64 + tm * 8 + 4];
    float4 bv = *(float4*)&sB[k * 128 + tn * 4];
    float av[8] = {a0.x, a0.y, a0.z, a0.w, a1.x, a1.y, a1.z, a1.w};
    float bb[4] = {bv.x, bv.y, bv.z, bv.w};
#pragma unroll
    for (int i = 0; i < 8; ++i)
#pragma unroll
      for (int jj = 0; jj < 4; ++jj) acc[i][jj] = fmaf(av[i], bb[jj], acc[i][jj]);
  }
  float4 bv = *(const float4*)(b + tn * 4);
#pragma unroll
  for (int i = 0; i < 8; ++i) {
    int row = mbase + tm * 8 + i;
    if (row < N_NODES) {
      float4 o = {acc[i][0] + bv.x, acc[i][1] + bv.y, acc[i][2] + bv.z, acc[i][3] + bv.w};
      *(float4*)(h + (size_t)row * HID + tn * 4) = o;
    }
  }
}

// ======================= CSR build =======================
__global__ __launch_bounds__(256) void hist_kernel(
    const int* __restrict__ dst, int* __restrict__ counts) {
  int e = blockIdx.x * 256 + threadIdx.x;
  if (e < N_EDGES) atomicAdd(&counts[dst[e]], 1);
}

#define SCAN_BLK 98  // ceil(100000/1024)
__global__ __launch_bounds__(256) void scan_partial(
    const int* __restrict__ cnt, int* __restrict__ partial) {
  __shared__ int sdata[256];
  int b = blockIdx.x, t = threadIdx.x;
  int sum = 0;
  for (int i = t; i < 1024; i += 256) {
    int idx = b * 1024 + i;
    sum += (idx < N_NODES) ? cnt[idx] : 0;
  }
  sdata[t] = sum; __syncthreads();
  for (int s = 128; s > 0; s >>= 1) {
    if (t < s) sdata[t] += sdata[t + s];
    __syncthreads();
  }
  if (t == 0) partial[b] = sdata[0];
}

__global__ void scan_sums(const int* __restrict__ partial,
                          int* __restrict__ partialScan, int* __restrict__ rowptr) {
  if (threadIdx.x == 0) {
    int acc = 0;
    for (int i = 0; i < SCAN_BLK; ++i) { partialScan[i] = acc; acc += partial[i]; }
    rowptr[N_NODES] = acc;
  }
}

__global__ __launch_bounds__(256) void scan_final(
    const int* __restrict__ cnt, const int* __restrict__ partialScan,
    int* __restrict__ rowptr, int* __restrict__ cur) {
  __shared__ int sdata[256];
  int b = blockIdx.x, t = threadIdx.x;
  int i0 = b * 1024 + t * 4;
  int c[4]; int s = 0;
#pragma unroll
  for (int j = 0; j < 4; ++j) {
    c[j] = (i0 + j < N_NODES) ? cnt[i0 + j] : 0;
    s += c[j];
  }
  sdata[t] = s; __syncthreads();
  for (int d = 1; d < 256; d <<= 1) {
    int u = (t >= d) ? sdata[t - d] : 0;
    __syncthreads();
    sdata[t] += u;
    __syncthreads();
  }
  int off = sdata[t] - s + partialScan[b];
#pragma unroll
  for (int j = 0; j < 4; ++j) {
    int idx = i0 + j;
    if (idx < N_NODES) { rowptr[idx] = off; cur[idx] = off; off += c[j]; }
  }
}

__global__ __launch_bounds__(256) void scatter_kernel(
    const int* __restrict__ dst, const int* __restrict__ src,
    int* __restrict__ cur, int* __restrict__ perm, int* __restrict__ srcp) {
  int e = blockIdx.x * 256 + threadIdx.x;
  if (e < N_EDGES) {
    int slot = atomicAdd(&cur[dst[e]], 1);
    perm[slot] = e;
    srcp[slot] = src[e];
  }
}

// ==== one-time: ea rows, permuted to CSR slot order, packed in MFMA
// A-fragment layout (bf16) so edge_emb loads fragments straight from global ====
__global__ __launch_bounds__(256) void build_eafrag(
    const float* __restrict__ ea, const int* __restrict__ perm,
    unsigned short* __restrict__ frag) {
  int slot = blockIdx.x * 256 + threadIdx.x;
  if (slot >= N_EDGES) return;
  int e = perm[slot];
  const float4* row = (const float4*)(ea + (size_t)e * EDGE_DIM);
  unsigned short* dp = frag + ((size_t)(slot >> 7)) * 4096 +
                       (size_t)(((slot & 127) >> 4)) * 512 + (slot & 15) * 8;
#pragma unroll
  for (int kg = 0; kg < 4; ++kg) {
    float4 v0 = row[kg * 2], v1 = row[kg * 2 + 1];
    short8 pk = {(short)f2bf(v0.x), (short)f2bf(v0.y), (short)f2bf(v0.z), (short)f2bf(v0.w),
                 (short)f2bf(v1.x), (short)f2bf(v1.y), (short)f2bf(v1.z), (short)f2bf(v1.w)};
    *(short8*)(dp + kg * 128) = pk;
  }
}

// ==== phase 1: m[slot] = relu(h[srcp[slot]] + ea_perm[slot] @ ew + eb), bf16 ====
// A/B fragments loaded directly from global (pre-packed). emb staged in LDS,
// then pass 2 does coalesced h-gather + relu + coalesced bf16 store.
__global__ __launch_bounds__(256) void edge_emb_kernel(
    const float* __restrict__ h, const unsigned short* __restrict__ eafrag,
    const int* __restrict__ srcp, const unsigned short* __restrict__ ewt,
    const float* __restrict__ eb, unsigned short* __restrict__ mout) {
  __shared__ float emb[128 * 132];  // stride 132 -> 2-way-max bank aliasing
  __shared__ int sidx[128];
  int tid = threadIdx.x, lane = tid & 63, wave = tid >> 6;
  int wm = wave & 1, wn = wave >> 1;
  int sbase = blockIdx.x * 128;
  if (tid < 128) {
    int sl = sbase + tid;
    sidx[tid] = (sl < N_EDGES) ? srcp[sl] : 0;
  }
  const short8* Af = (const short8*)(eafrag) + (size_t)blockIdx.x * 512;
  const short8* Bh = (const short8*)(ewt);
  const short8* Bl = (const short8*)(ewt + 4096);
  short8 af[4], bh[4], bl[4];
#pragma unroll
  for (int mt = 0; mt < 4; ++mt) af[mt] = Af[(wm * 4 + mt) * 64 + lane];
#pragma unroll
  for (int nt = 0; nt < 4; ++nt) {
    bh[nt] = Bh[(wn * 4 + nt) * 64 + lane];
    bl[nt] = Bl[(wn * 4 + nt) * 64 + lane];
  }
  const f32x4 zf = {0.f, 0.f, 0.f, 0.f};
  f32x4 acc[4][4];
#pragma unroll
  for (int mt = 0; mt < 4; ++mt)
#pragma unroll
    for (int nt = 0; nt < 4; ++nt) {
      acc[mt][nt] = MFMA16(af[mt], bh[nt], zf);
      acc[mt][nt] = MFMA16(af[mt], bl[nt], acc[mt][nt]);
    }
  int q = lane >> 4, r = lane & 15;
#pragma unroll
  for (int nt = 0; nt < 4; ++nt) {
    int n = wn * 64 + nt * 16 + r;
    float ebv = eb[n];
#pragma unroll
    for (int mt = 0; mt < 4; ++mt) {
      int rowb = (wm * 4 + mt) * 16 + q * 4;
#pragma unroll
      for (int i2 = 0; i2 < 4; ++i2)
        emb[(rowb + i2) * 132 + n] = acc[mt][nt][i2] + ebv;
    }
  }
  __syncthreads();
#pragma unroll
  for (int it = 0; it < 16; ++it) {
    int idx = it * 256 + tid;
    int row = idx >> 5, c4 = (idx & 31) * 4;
    int sl = sbase + row;
    int s = sidx[row];
    float4 hv = *(const float4*)(h + (size_t)s * HID + c4);
    float4 ev = *(const float4*)(emb + row * 132 + c4);
    short4v pk = {(short)f2bf(fmaxf(ev.x + hv.x, 0.f)),
                  (short)f2bf(fmaxf(ev.y + hv.y, 0.f)),
                  (short)f2bf(fmaxf(ev.z + hv.z, 0.f)),
                  (short)f2bf(fmaxf(ev.w + hv.w, 0.f))};
    if (sl < N_EDGES) *(short4v*)(mout + (size_t)sl * HID + c4) = pk;
  }
}

// ==== phase 2: agg[node] = sum of m rows rowptr[node]..rowptr[node+1] ====
// m is in CSR order -> each segment is a contiguous streaming read.
__global__ __launch_bounds__(256) void seg_sum_kernel(
    const unsigned short* __restrict__ m, const int* __restrict__ rowptr,
    float* __restrict__ agg) {
  int lane = threadIdx.x & 63;
  int wid = blockIdx.x * 4 + (threadIdx.x >> 6);
  int nw = gridDim.x * 4;
  const unsigned* mu = (const unsigned*)m;
  for (int node = wid; node < N_NODES; node += nw) {
    int beg = rowptr[node], end = rowptr[node + 1];
    float2 acc = {0.f, 0.f};
    const unsigned* p = mu + (size_t)beg * 64 + lane;
    int n = end - beg;
    int i = 0;
    for (; i + 4 <= n; i += 4) {
      unsigned u0 = p[0], u1 = p[64], u2 = p[128], u3 = p[192];
      p += 256;
      acc.x += __uint_as_float(u0 << 16) + __uint_as_float(u1 << 16) +
               __uint_as_float(u2 << 16) + __uint_as_float(u3 << 16);
      acc.y += __uint_as_float(u0 & 0xffff0000u) + __uint_as_float(u1 & 0xffff0000u) +
               __uint_as_float(u2 & 0xffff0000u) + __uint_as_float(u3 & 0xffff0000u);
    }
    for (; i < n; ++i) {
      unsigned u = p[0];
      p += 64;
      acc.x += __uint_as_float(u << 16);
      acc.y += __uint_as_float(u & 0xffff0000u);
    }
    *(float2*)(agg + (size_t)node * HID + lane * 2) = acc;
  }
}

// ======== fallback aggregation (small-workspace path) ========
__global__ __launch_bounds__(256) void agg_gather_kernel(
    const float* __restrict__ h, const float* __restrict__ ea,
    const int* __restrict__ srcp, const int* __restrict__ perm,
    const int* __restrict__ rowptr,
    const float* __restrict__ ew, const float* __restrict__ eb,
    float* __restrict__ agg) {
  int tid = threadIdx.x, lane = tid & 63;
  int wid = blockIdx.x * 4 + (tid >> 6);
  int nwaves = gridDim.x * 4;
  const float2* ew2 = (const float2*)ew;
  float2 ebv = *(const float2*)(eb + lane * 2);

  for (int node = wid; node < N_NODES; node += nwaves) {
    int beg = rowptr[node], end = rowptr[node + 1];
    float2 acc = {0.f, 0.f};
    for (int i = beg; i < end; ++i) {
      int s0 = srcp[i];
      int e0 = perm[i];
      float2 h0 = *(const float2*)(h + (size_t)s0 * HID + lane * 2);
      const float4* ea0 = (const float4*)(ea + (size_t)e0 * EDGE_DIM);
      float2 m0 = ebv;
#pragma unroll
      for (int k4 = 0; k4 < 8; ++k4) {
        float4 a0 = ea0[k4];
        float a0v[4] = {a0.x, a0.y, a0.z, a0.w};
#pragma unroll
        for (int j = 0; j < 4; ++j) {
          float2 w = ew2[(k4 * 4 + j) * 64 + lane];
          m0.x = fmaf(a0v[j], w.x, m0.x);
          m0.y = fmaf(a0v[j], w.y, m0.y);
        }
      }
      acc.x += fmaxf(m0.x + h0.x, 0.f);
      acc.y += fmaxf(m0.y + h0.y, 0.f);
    }
    *(float2*)(agg + (size_t)node * HID + lane * 2) = acc;
  }
}

// ======== node MLP via split-bf16 MFMA ========
__global__ __launch_bounds__(256) void mlp_mfma(
    const float* __restrict__ h, const float* __restrict__ agg,
    const unsigned short* __restrict__ wl,
    const float* __restrict__ b1, const float* __restrict__ b2,
    float* __restrict__ hout) {
  __shared__ unsigned short lds[40960];  // 80 KB
  unsigned short* sAh = lds;
  unsigned short* sAl = lds + 4096;
  unsigned short* sBh = lds + 8192;
  unsigned short* sBl = lds + 12288;
  unsigned short* t1h = lds;
  unsigned short* t1l = lds + 16384;
  unsigned short* sB2h = lds + 32768;
  unsigned short* sB2l = lds + 36864;
  const unsigned short* w1h = wl;
  const unsigned short* w1l = wl + 16384;
  const unsigned short* w2h = wl + 32768;
  const unsigned short* w2l = wl + 49152;
  int tid = threadIdx.x, lane = tid & 63, wave = tid >> 6;
  int wm = wave & 1, wn = wave >> 1;
  int mbase = blockIdx.x * 128;
  const f32x4 zf = {0.f, 0.f, 0.f, 0.f};

  f32x4 acc[4][4];
#pragma unroll
  for (int a = 0; a < 4; ++a)
#pragma unroll
    for (int bq = 0; bq < 4; ++bq) acc[a][bq] = zf;

  for (int c = 0; c < 4; ++c) {
    __syncthreads();
#pragma unroll
    for (int it = 0; it < 4; ++it) {
      int idx = it * 256 + tid;
      int m = idx >> 3, k4 = (idx & 7) * 4;
      int row = mbase + m; if (row >= N_NODES) row = N_NODES - 1;
      size_t g = (size_t)row * HID + c * 32 + k4;
      float4 hv = *(const float4*)(h + g);
      float4 av = *(const float4*)(agg + g);
      float z0 = hv.x + av.x, z1 = hv.y + av.y, z2 = hv.z + av.z, z3 = hv.w + av.w;
      unsigned short h0 = f2bf(z0), h1 = f2bf(z1), h2 = f2bf(z2), h3 = f2bf(z3);
      int slot = ((m >> 4) * 4 + (k4 >> 3)) * 16 + (m & 15);
      int off = slot * 8 + (k4 & 7);
      short4v ph = {(short)h0, (short)h1, (short)h2, (short)h3};
      short4v pl = {(short)f2bf(z0 - bf2f(h0)), (short)f2bf(z1 - bf2f(h1)),
                    (short)f2bf(z2 - bf2f(h2)), (short)f2bf(z3 - bf2f(h3))};
      *(short4v*)(sAh + off) = ph;
      *(short4v*)(sAl + off) = pl;
    }
#pragma unroll
    for (int it = 0; it < 2; ++it) {
      int s = it * 256 + tid;
      int ntile = s >> 6, kgrp = (s >> 4) & 3, nrow = s & 15;
      int goff = (ntile * 16 + nrow) * 128 + c * 32 + kgrp * 8;
      *(short8*)(sBh + s * 8) = *(const short8*)(w1h + goff);
      *(short8*)(sBl + s * 8) = *(const short8*)(w1l + goff);
    }
    __syncthreads();
    short8 ah[4], al[4], bh[4], bl[4];
#pragma unroll
    for (int mt = 0; mt < 4; ++mt) {
      ah[mt] = *(short8*)(sAh + ((wm * 4 + mt) * 64 + lane) * 8);
      al[mt] = *(short8*)(sAl + ((wm * 4 + mt) * 64 + lane) * 8);
    }
#pragma unroll
    for (int nt = 0; nt < 4; ++nt) {
      bh[nt] = *(short8*)(sBh + ((wn * 4 + nt) * 64 + lane) * 8);
      bl[nt] = *(short8*)(sBl + ((wn * 4 + nt) * 64 + lane) * 8);
    }
#pragma unroll
    for (int mt = 0; mt < 4; ++mt)
#pragma unroll
      for (int nt = 0; nt < 4; ++nt) {
        acc[mt][nt] = MFMA16(ah[mt], bh[nt], acc[mt][nt]);
        acc[mt][nt] = MFMA16(ah[mt], bl[nt], acc[mt][nt]);
        acc[mt][nt] = MFMA16(al[mt], bh[nt], acc[mt][nt]);
      }
  }
  __syncthreads();
  int q = lane >> 4, r = lane & 15;
#pragma unroll
  for (int nt = 0; nt < 4; ++nt) {
    int n = wn * 64 + nt * 16 + r;
    float b1v = b1[n];
    int kgrp = n >> 3, jj = n & 7;
#pragma unroll
    for (int mt = 0; mt < 4; ++mt) {
      int mtg = wm * 4 + mt;
#pragma unroll
      for (int i2 = 0; i2 < 4; ++i2) {
        int mrow = q * 4 + i2;
        float val = fmaxf(acc[mt][nt][i2] + b1v, 0.f);
        unsigned short hi = f2bf(val);
        int idx = ((mtg * 16 + kgrp) * 16 + mrow) * 8 + jj;
        t1h[idx] = hi;
        t1l[idx] = f2bf(val - bf2f(hi));
      }
    }
  }

  f32x4 acc2[4][4];
#pragma unroll
  for (int a = 0; a < 4; ++a)
#pragma unroll
    for (int bq = 0; bq < 4; ++bq) acc2[a][bq] = zf;

  for (int kc = 0; kc < 4; ++kc) {
    __syncthreads();
#pragma unroll
    for (int it = 0; it < 2; ++it) {
      int s = it * 256 + tid;
      int ntile = s >> 6, kgrp = (s >> 4) & 3, nrow = s & 15;
      int goff = (ntile * 16 + nrow) * 128 + kc * 32 + kgrp * 8;
      *(short8*)(sB2h + s * 8) = *(const short8*)(w2h + goff);
      *(short8*)(sB2l + s * 8) = *(const short8*)(w2l + goff);
    }
    __syncthreads();
    short8 ah[4], al[4], bh[4], bl[4];
#pragma unroll
    for (int mt = 0; mt < 4; ++mt) {
      int mtg = wm * 4 + mt;
      int idx = ((mtg * 16 + kc * 4 + q) * 16 + r) * 8;
      ah[mt] = *(short8*)(t1h + idx);
      al[mt] = *(short8*)(t1l + idx);
    }
#pragma unroll
    for (int nt = 0; nt < 4; ++nt) {
      bh[nt] = *(short8*)(sB2h + ((wn * 4 + nt) * 64 + lane) * 8);
      bl[nt] = *(short8*)(sB2l + ((wn * 4 + nt) * 64 + lane) * 8);
    }
#pragma unroll
    for (int mt = 0; mt < 4; ++mt)
#pragma unroll
      for (int nt = 0; nt < 4; ++nt) {
        acc2[mt][nt] = MFMA16(ah[mt], bh[nt], acc2[mt][nt]);
        acc2[mt][nt] = MFMA16(ah[mt], bl[nt], acc2[mt][nt]);
        acc2[mt][nt] = MFMA16(al[mt], bh[nt], acc2[mt][nt]);
      }
  }
#pragma unroll
  for (int nt = 0; nt < 4; ++nt) {
    int n = wn * 64 + nt * 16 + r;
    float b2v = b2[n];
#pragma unroll
    for (int mt = 0; mt < 4; ++mt) {
      int mtg = wm * 4 + mt;
#pragma unroll
      for (int i2 = 0; i2 < 4; ++i2) {
        int row = mbase + mtg * 16 + q * 4 + i2;
        if (row < N_NODES)
          hout[(size_t)row * HID + n] = fmaxf(acc2[mt][nt][i2] + b2v, 0.f);
      }
    }
  }
}

// ======== classifier via bf16 MFMA ========
__global__ __launch_bounds__(256) void cls_mfma(
    const float* __restrict__ h, const float* __restrict__ ea,
    const int* __restrict__ src, const int* __restrict__ dst,
    const unsigned short* __restrict__ w1t, const unsigned short* __restrict__ w2t,
    const float* __restrict__ b1, const float* __restrict__ b2,
    float* __restrict__ out) {
  __shared__ unsigned short lds[20480];  // 40 KB
  unsigned short* sA = lds;
  unsigned short* sB = lds + 4096;
  unsigned short* t1 = lds;
  unsigned short* sB2 = lds + 16384;
  __shared__ int sidx[256];
  int tid = threadIdx.x, lane = tid & 63, wave = tid >> 6;
  int wm = wave & 1, wn = wave >> 1;
  int ebase = blockIdx.x * 128;
  const f32x4 zf = {0.f, 0.f, 0.f, 0.f};

  {
    int e0 = ebase + (tid & 127);
    if (e0 >= N_EDGES) e0 = N_EDGES - 1;
    sidx[tid] = (tid < 128 ? src : dst)[e0];
  }

  f32x4 acc[4][4];
#pragma unroll
  for (int a = 0; a < 4; ++a)
#pragma unroll
    for (int bq = 0; bq < 4; ++bq) acc[a][bq] = zf;

  for (int c = 0; c < 9; ++c) {
    __syncthreads();
#pragma unroll
    for (int it = 0; it < 4; ++it) {
      int idx = it * 256 + tid;
      int m = idx >> 3, k4 = (idx & 7) * 4;
      const float* rp;
      if (c < 4)      rp = h + (size_t)sidx[m] * HID + c * 32 + k4;
      else if (c < 8) rp = h + (size_t)sidx[128 + m] * HID + (c - 4) * 32 + k4;
      else {
        int e8 = ebase + m; if (e8 >= N_EDGES) e8 = N_EDGES - 1;
        rp = ea + (size_t)e8 * EDGE_DIM + k4;
      }
      float4 v = *(const float4*)rp;
      int slot = ((m >> 4) * 4 + (k4 >> 3)) * 16 + (m & 15);
      short4v pk = {(short)f2bf(v.x), (short)f2bf(v.y), (short)f2bf(v.z), (short)f2bf(v.w)};
      *(short4v*)(sA + slot * 8 + (k4 & 7)) = pk;
    }
#pragma unroll
    for (int it = 0; it < 2; ++it) {
      int s = it * 256 + tid;
      int ntile = s >> 6, kgrp = (s >> 4) & 3, nrow = s & 15;
      *(short8*)(sB + s * 8) = *(const short8*)(w1t + (ntile * 16 + nrow) * 288 + c * 32 + kgrp * 8);
    }
    __syncthreads();
    short8 af[4], bfv[4];
#pragma unroll
    for (int mt = 0; mt < 4; ++mt)
      af[mt] = *(short8*)(sA + ((wm * 4 + mt) * 64 + lane) * 8);
#pragma unroll
    for (int nt = 0; nt < 4; ++nt)
      bfv[nt] = *(short8*)(sB + ((wn * 4 + nt) * 64 + lane) * 8);
#pragma unroll
    for (int mt = 0; mt < 4; ++mt)
#pragma unroll
      for (int nt = 0; nt < 4; ++nt)
        acc[mt][nt] = MFMA16(af[mt], bfv[nt], acc[mt][nt]);
  }
  __syncthreads();
  int q = lane >> 4, r = lane & 15;
#pragma unroll
  for (int nt = 0; nt < 4; ++nt) {
    int n = wn * 64 + nt * 16 + r;
    float b1v = b1[n];
    int kgrp = n >> 3, jj = n & 7;
#pragma unroll
    for (int mt = 0; mt < 4; ++mt) {
      int mtg = wm * 4 + mt;
#pragma unroll
      for (int i2 = 0; i2 < 4; ++i2) {
        int mrow = q * 4 + i2;
        float val = fmaxf(acc[mt][nt][i2] + b1v, 0.f);
        t1[((mtg * 16 + kgrp) * 16 + mrow) * 8 + jj] = f2bf(val);
      }
    }
  }
#pragma unroll
  for (int it = 0; it < 2; ++it) {
    int s = it * 256 + tid;
    int ntile = s >> 8, kgrp = (s >> 4) & 15, nrow = s & 15;
    *(short8*)(sB2 + s * 8) = *(const short8*)(w2t + (ntile * 16 + nrow) * 128 + kgrp * 8);
  }
  __syncthreads();

  f32x4 acc2[2][2];
  acc2[0][0] = zf; acc2[0][1] = zf; acc2[1][0] = zf; acc2[1][1] = zf;
#pragma unroll
  for (int kc = 0; kc < 4; ++kc) {
    short8 a0 = *(short8*)(t1 + (((wave * 2 + 0) * 16 + kc * 4 + q) * 16 + r) * 8);
    short8 a1 = *(short8*)(t1 + (((wave * 2 + 1) * 16 + kc * 4 + q) * 16 + r) * 8);
    short8 b0 = *(short8*)(sB2 + ((0 * 16 + kc * 4 + q) * 16 + r) * 8);
    short8 b1f = *(short8*)(sB2 + ((1 * 16 + kc * 4 + q) * 16 + r) * 8);
    acc2[0][0] = MFMA16(a0, b0, acc2[0][0]);
    acc2[0][1] = MFMA16(a0, b1f, acc2[0][1]);
    acc2[1][0] = MFMA16(a1, b0, acc2[1][0]);
    acc2[1][1] = MFMA16(a1, b1f, acc2[1][1]);
  }
#pragma unroll
  for (int nt2 = 0; nt2 < 2; ++nt2) {
    int n = nt2 * 16 + r;
    float b2v = (n < OUT_DIM) ? b2[n] : 0.f;
#pragma unroll
    for (int mt2 = 0; mt2 < 2; ++mt2) {
      int mtg = wave * 2 + mt2;
#pragma unroll
      for (int i2 = 0; i2 < 4; ++i2) {
        int e = ebase + mtg * 16 + q * 4 + i2;
        if (n < OUT_DIM && e < N_EDGES)
          out[(size_t)e * OUT_DIM + n] = acc2[mt2][nt2][i2] + b2v;
      }
    }
  }
}

extern "C" void kernel_launch(void* const* d_in, const int* in_sizes, int n_in,
                              void* d_out, int out_size, void* d_ws, size_t ws_size,
                              hipStream_t stream) {
  const float* x = (const float*)d_in[0];
  const int* ei = (const int*)d_in[1];
  const float* ea = (const float*)d_in[2];
  const float* lin1_w = (const float*)d_in[3];
  const float* lin1_b = (const float*)d_in[4];
  const int* src = ei;
  const int* dst = ei + N_EDGES;

  const size_t NH = (size_t)N_NODES * HID;
  float* bufA = (float*)d_ws;
  float* bufB = bufA + NH;
  int* ibase = (int*)(bufB + NH);
  int* rowptr = ibase;                 // N_NODES+1
  int* cur = ibase + 100004;           // N_NODES
  int* counts = ibase + 200004;        // N_NODES
  int* perm = ibase + 300004;          // N_EDGES
  int* partial = ibase + 900004;       // 128
  int* partialScan = ibase + 900132;   // 128
  int* srcp = ibase + 900260;          // N_EDGES
  // big-workspace extras: m (bf16, CSR order) + ea fragments (bf16)
  unsigned short* mbuf = (unsigned short*)(ibase + 1500264);
  unsigned short* eafrag = mbuf + (size_t)N_EDGES * HID;
  size_t need = (size_t)((char*)(eafrag + (size_t)N_EDGES * EDGE_DIM) - (char*)d_ws) +
                (size_t)W_TOTAL * 2 + 4096;
  bool big = ws_size >= need;
  // prepped weights at the END of ws
  unsigned short* wbase = (unsigned short*)((((uintptr_t)d_ws + ws_size) - (size_t)W_TOTAL * 2) & ~(uintptr_t)255);

  prep_weights<<<(163840 + 255) / 256, 256, 0, stream>>>(
      (const float*)d_in[23], (const float*)d_in[25],
      (const float*)d_in[7], (const float*)d_in[9],
      (const float*)d_in[13], (const float*)d_in[15],
      (const float*)d_in[19], (const float*)d_in[21],
      (const float*)d_in[5], (const float*)d_in[11], (const float*)d_in[17],
      wbase);

  lin1_kernel<<<(N_NODES + 63) / 64, 256, 0, stream>>>(x, lin1_w, lin1_b, bufA);

  // ---- CSR build (once; shared by all 3 layers) ----
  hipMemsetAsync(counts, 0, N_NODES * sizeof(int), stream);
  hist_kernel<<<(N_EDGES + 255) / 256, 256, 0, stream>>>(dst, counts);
  scan_partial<<<SCAN_BLK, 256, 0, stream>>>(counts, partial);
  scan_sums<<<1, 64, 0, stream>>>(partial, partialScan, rowptr);
  scan_final<<<SCAN_BLK, 256, 0, stream>>>(counts, partialScan, rowptr, cur);
  scatter_kernel<<<(N_EDGES + 255) / 256, 256, 0, stream>>>(dst, src, cur, perm, srcp);
  if (big)
    build_eafrag<<<(N_EDGES + 255) / 256, 256, 0, stream>>>(ea, perm, eafrag);

  float* hcur = bufA;
  float* aux = bufB;
  for (int c = 0; c < 3; ++c) {
    const float* ew = (const float*)d_in[5 + c * 6 + 0];
    const float* eb = (const float*)d_in[5 + c * 6 + 1];
    const float* b1 = (const float*)d_in[5 + c * 6 + 3];
    const float* b2 = (const float*)d_in[5 + c * 6 + 5];
    if (big) {
      edge_emb_kernel<<<(N_EDGES + 127) / 128, 256, 0, stream>>>(
          hcur, eafrag, srcp, wbase + OFF_EWT(c), eb, mbuf);
      seg_sum_kernel<<<2048, 256, 0, stream>>>(mbuf, rowptr, aux);
    } else {
      agg_gather_kernel<<<2048, 256, 0, stream>>>(
          hcur, ea, srcp, perm, rowptr, ew, eb, aux);
    }
    mlp_mfma<<<(N_NODES + 127) / 128, 256, 0, stream>>>(
        hcur, aux, wbase + OFF_LAYER(c), b1, b2, aux);
    float* tmp = hcur; hcur = aux; aux = tmp;
  }

  const float* cb1 = (const float*)d_in[24];
  const float* cb2 = (const float*)d_in[26];
  cls_mfma<<<(N_EDGES + 127) / 128, 256, 0, stream>>>(
      hcur, ea, src, dst, wbase + OFF_CW1T, wbase + OFF_CW2T, cb1, cb2, (float*)d_out);
}